// Round 5
// baseline (1271.723 us; speedup 1.0000x reference)
//
#include <hip/hip_runtime.h>

#define N_NODES 100000
#define N_EDGES 1600000
#define FEAT 128
#define LAYERS 4
#define SCAN_BLK 256
#define N_SCAN_BLKS ((N_NODES + SCAN_BLK - 1) / SCAN_BLK)  // 391
#define NBKT ((N_NODES + 511) >> 9)                        // 196 buckets x 512 nodes
#define P1_CHUNK 4096
#define N_P1_BLKS ((N_EDGES + P1_CHUNK - 1) / P1_CHUNK)    // 391

typedef __attribute__((ext_vector_type(8))) short bf16x8;
typedef __attribute__((ext_vector_type(4))) float f32x4;

__device__ __forceinline__ unsigned short f2b(float f) {   // f32 -> bf16 RNE
    union { float f; unsigned int u; } v; v.f = f;
    unsigned int u = v.u;
    return (unsigned short)((u + 0x7fffu + ((u >> 16) & 1u)) >> 16);
}

// ---------------- CSR build ----------------
// deg count + bucket count (LDS-aggregated bucket atomics)
__global__ __launch_bounds__(256) void count_deg_kernel(const int* __restrict__ dst,
                                                        int* __restrict__ deg,
                                                        int* __restrict__ bkt_cnt) {
    __shared__ int h[NBKT];
    for (int i = threadIdx.x; i < NBKT; i += 256) h[i] = 0;
    __syncthreads();
    const int base = blockIdx.x * P1_CHUNK;
    for (int i = threadIdx.x; i < P1_CHUNK; i += 256) {
        int e = base + i;
        if (e < N_EDGES) {
            int d = dst[e];
            atomicAdd(&deg[d], 1);
            atomicAdd(&h[d >> 9], 1);
        }
    }
    __syncthreads();
    for (int i = threadIdx.x; i < NBKT; i += 256)
        if (h[i]) atomicAdd(&bkt_cnt[i], h[i]);
}

__global__ __launch_bounds__(SCAN_BLK) void blk_sum_kernel(const int* __restrict__ deg,
                                                           int* __restrict__ blk_sums) {
    int i = blockIdx.x * SCAN_BLK + threadIdx.x;
    int v = (i < N_NODES) ? deg[i] : 0;
#pragma unroll
    for (int off = 32; off; off >>= 1) v += __shfl_down(v, off, 64);
    __shared__ int ws_[SCAN_BLK / 64];
    if ((threadIdx.x & 63) == 0) ws_[threadIdx.x >> 6] = v;
    __syncthreads();
    if (threadIdx.x == 0) {
        int s = 0;
#pragma unroll
        for (int w = 0; w < SCAN_BLK / 64; ++w) s += ws_[w];
        blk_sums[blockIdx.x] = s;
    }
}

// single block: scan 391 deg-block sums AND 196 bucket counts
__global__ __launch_bounds__(512) void scan_all_kernel(int* __restrict__ blk_sums,
                                                       const int* __restrict__ bkt_cnt,
                                                       int* __restrict__ bkt_start,
                                                       int* __restrict__ bkt_cursor) {
    __shared__ int s[512];
    __shared__ int b[256];
    const int t = threadIdx.x;
    s[t] = (t < N_SCAN_BLKS) ? blk_sums[t] : 0;
    if (t < 256) b[t] = (t < NBKT) ? bkt_cnt[t] : 0;
    __syncthreads();
    for (int off = 1; off < 512; off <<= 1) {
        int v = (t >= off) ? s[t - off] : 0;
        __syncthreads();
        s[t] += v;
        __syncthreads();
    }
    for (int off = 1; off < 256; off <<= 1) {
        int v = (t < 256 && t >= off) ? b[t - off] : 0;
        __syncthreads();
        if (t < 256) b[t] += v;
        __syncthreads();
    }
    if (t < N_SCAN_BLKS) blk_sums[t] = (t == 0) ? 0 : s[t - 1];
    if (t < NBKT) {
        int st = (t == 0) ? 0 : b[t - 1];
        bkt_start[t] = st;
        bkt_cursor[t] = st;
    }
    if (t == 0) bkt_start[NBKT] = N_EDGES;
}

__global__ __launch_bounds__(SCAN_BLK) void write_rowptr_kernel(
    const int* __restrict__ deg, const int* __restrict__ blk_off,
    int* __restrict__ row_ptr) {
    __shared__ int s[SCAN_BLK];
    const int t = threadIdx.x;
    const int i = blockIdx.x * SCAN_BLK + t;
    int v = (i < N_NODES) ? deg[i] : 0;
    s[t] = v;
    __syncthreads();
    for (int off = 1; off < SCAN_BLK; off <<= 1) {
        int u = (t >= off) ? s[t - off] : 0;
        __syncthreads();
        s[t] += u;
        __syncthreads();
    }
    int excl = s[t] - v + blk_off[blockIdx.x];
    if (i < N_NODES) row_ptr[i] = excl;
    if (i == 0) row_ptr[N_NODES] = N_EDGES;
}

// pass1: scatter (src,dst) grouped by bucket; per-block contiguous runs
__global__ __launch_bounds__(256) void bucket_scatter_kernel(
    const int* __restrict__ src, const int* __restrict__ dst,
    int* __restrict__ bkt_cursor, int2* __restrict__ ebuf) {
    __shared__ int h[NBKT], base[NBKT], cur[NBKT];
    for (int i = threadIdx.x; i < NBKT; i += 256) h[i] = 0;
    __syncthreads();
    const int b0 = blockIdx.x * P1_CHUNK;
    for (int i = threadIdx.x; i < P1_CHUNK; i += 256) {
        int e = b0 + i;
        if (e < N_EDGES) atomicAdd(&h[dst[e] >> 9], 1);
    }
    __syncthreads();
    for (int i = threadIdx.x; i < NBKT; i += 256) {
        cur[i] = 0;
        base[i] = h[i] ? atomicAdd(&bkt_cursor[i], h[i]) : 0;
    }
    __syncthreads();
    for (int i = threadIdx.x; i < P1_CHUNK; i += 256) {
        int e = b0 + i;
        if (e < N_EDGES) {
            int d = dst[e];
            int bk = d >> 9;
            int pos = base[bk] + atomicAdd(&cur[bk], 1);
            ebuf[pos] = make_int2(src[e], d);
        }
    }
}

// pass2: per-bucket CSR scatter with LDS cursors (writes land in ~32KB window)
__global__ __launch_bounds__(256) void csr_scatter_kernel(
    const int2* __restrict__ ebuf, const int* __restrict__ bkt_start,
    const int* __restrict__ row_ptr, int* __restrict__ edge_src) {
    __shared__ int cur[512];
    const int bk = blockIdx.x;
    const int n0 = bk << 9;
    for (int i = threadIdx.x; i < 512; i += 256) {
        int n = n0 + i;
        cur[i] = (n < N_NODES) ? row_ptr[n] : 0;
    }
    __syncthreads();
    const int s = bkt_start[bk], e = bkt_start[bk + 1];
    for (int i = s + threadIdx.x; i < e; i += 256) {
        int2 ed = ebuf[i];
        int pos = atomicAdd(&cur[ed.y - n0], 1);
        edge_src[pos] = ed.x;
    }
}

// ---------------- weight convert: Wt[m][n][k] = bf16(W[m][k][n]) ----------------
__global__ __launch_bounds__(256) void convert_wt_kernel(
    const float* __restrict__ Wp, const float* __restrict__ Ws,
    const float* __restrict__ Wn, unsigned short* __restrict__ wt) {
    __shared__ float tile[64][65];
    const int m = blockIdx.x >> 2;
    const int tij = blockIdx.x & 3;
    const int ti = tij >> 1, tj = tij & 1;
    const float* W = (m < 4) ? Wp + (size_t)m * 16384
                   : (m < 8) ? Ws + (size_t)(m - 4) * 16384
                             : Wn + (size_t)(m - 8) * 16384;
#pragma unroll
    for (int i = 0; i < 16; ++i) {
        int e = i * 256 + threadIdx.x;
        int r = e >> 6, c = e & 63;
        tile[r][c] = W[(size_t)(ti * 64 + r) * 128 + tj * 64 + c];
    }
    __syncthreads();
#pragma unroll
    for (int i = 0; i < 16; ++i) {
        int e = i * 256 + threadIdx.x;
        int r = e >> 6, c = e & 63;
        wt[(size_t)m * 16384 + (size_t)(tj * 64 + r) * 128 + ti * 64 + c] = f2b(tile[c][r]);
    }
}

// ---------------- MFMA GEMM, 3 modes ----------------
// MODE 0: yh = bf16(relu(x@W1 + bias))                     (layer h_pool)
// MODE 1: x' = relu(x@W1 + p@W2 + bias) -> yf (f32);
//         yh = bf16(relu(x'@Wnt + bias_n))                 (out fused w/ next h_pool)
// MODE 2: x' only -> yf                                    (last layer out)
// mfma_f32_16x16x32_bf16: A row=lane&15, k=8*(lane>>4)+j; B col=lane&15 same k;
// C/D col=lane&15, row=4*(lane>>4)+reg.
template <int MODE>
__global__ __launch_bounds__(256) void gemm_kernel(
    const float* __restrict__ x, const unsigned short* __restrict__ p,
    const unsigned short* __restrict__ W1t, const unsigned short* __restrict__ W2t,
    const float* __restrict__ bias,
    const unsigned short* __restrict__ Wnt, const float* __restrict__ bias_n,
    float* __restrict__ yf, unsigned short* __restrict__ yh) {
    __shared__ unsigned short xs[64 * FEAT];  // 16 KB, XOR-swizzled
    const int tid = threadIdx.x;
    const int wv = tid >> 6;
    const int lane = tid & 63;
    const int l15 = lane & 15;
    const int lhi = lane >> 4;
    const int n0 = blockIdx.x * 64;
    const int arow = 16 * wv + l15;
    const int rbase = n0 + 16 * wv + 4 * lhi;

    f32x4 acc[8];
#pragma unroll
    for (int t = 0; t < 8; ++t) acc[t] = (f32x4)(0.f);

    // ---- pass 0: x (f32 -> bf16) @ W1t ----
#pragma unroll
    for (int i = 0; i < 4; ++i) {
        int chunk = i * 256 + tid;
        int row = chunk >> 4, c8 = chunk & 15;
        int n = n0 + row;
        float4 v0 = make_float4(0.f, 0.f, 0.f, 0.f), v1 = v0;
        if (n < N_NODES) {
            const float4* g = (const float4*)(x + (size_t)n * FEAT + c8 * 8);
            v0 = g[0]; v1 = g[1];
        }
        unsigned short hh[8];
        hh[0] = f2b(v0.x); hh[1] = f2b(v0.y); hh[2] = f2b(v0.z); hh[3] = f2b(v0.w);
        hh[4] = f2b(v1.x); hh[5] = f2b(v1.y); hh[6] = f2b(v1.z); hh[7] = f2b(v1.w);
        int byte = (row * 256 + c8 * 16) ^ ((row & 7) << 4);
        *(bf16x8*)((char*)xs + byte) = *(bf16x8*)hh;
    }
    __syncthreads();
    {
        bf16x8 afrag[4];
#pragma unroll
        for (int kk = 0; kk < 4; ++kk) {
            int byte = (arow * 256 + (kk * 32 + lhi * 8) * 2) ^ ((arow & 7) << 4);
            afrag[kk] = *(const bf16x8*)((const char*)xs + byte);
        }
#pragma unroll
        for (int nt = 0; nt < 8; ++nt) {
            const int ncol = nt * 16 + l15;
#pragma unroll
            for (int kk = 0; kk < 4; ++kk) {
                bf16x8 bfrag = *(const bf16x8*)(W1t + (size_t)ncol * FEAT + kk * 32 + lhi * 8);
                acc[nt] = __builtin_amdgcn_mfma_f32_16x16x32_bf16(afrag[kk], bfrag, acc[nt], 0, 0, 0);
            }
        }
    }

    // ---- pass 1: p (bf16) @ W2t ----
    if (MODE >= 1) {
        __syncthreads();
#pragma unroll
        for (int i = 0; i < 4; ++i) {
            int chunk = i * 256 + tid;
            int row = chunk >> 4, c8 = chunk & 15;
            int n = n0 + row;
            float4 v = make_float4(0.f, 0.f, 0.f, 0.f);
            if (n < N_NODES) v = *(const float4*)(p + (size_t)n * FEAT + c8 * 8);
            int byte = (row * 256 + c8 * 16) ^ ((row & 7) << 4);
            *(float4*)((char*)xs + byte) = v;
        }
        __syncthreads();
        bf16x8 afrag[4];
#pragma unroll
        for (int kk = 0; kk < 4; ++kk) {
            int byte = (arow * 256 + (kk * 32 + lhi * 8) * 2) ^ ((arow & 7) << 4);
            afrag[kk] = *(const bf16x8*)((const char*)xs + byte);
        }
#pragma unroll
        for (int nt = 0; nt < 8; ++nt) {
            const int ncol = nt * 16 + l15;
#pragma unroll
            for (int kk = 0; kk < 4; ++kk) {
                bf16x8 bfrag = *(const bf16x8*)(W2t + (size_t)ncol * FEAT + kk * 32 + lhi * 8);
                acc[nt] = __builtin_amdgcn_mfma_f32_16x16x32_bf16(afrag[kk], bfrag, acc[nt], 0, 0, 0);
            }
        }
    }

    // ---- epilogue 1: bias + relu; write ----
    if (MODE >= 1) __syncthreads();  // all waves done reading xs before x' overwrite
#pragma unroll
    for (int nt = 0; nt < 8; ++nt) {
        const int col = nt * 16 + l15;
        const float bv = bias[col];
#pragma unroll
        for (int r = 0; r < 4; ++r) {
            int n = rbase + r;
            float v = fmaxf(acc[nt][r] + bv, 0.f);
            if (MODE == 0) {
                if (n < N_NODES) yh[(size_t)n * FEAT + col] = f2b(v);
            } else {
                if (n < N_NODES) yf[(size_t)n * FEAT + col] = v;
                if (MODE == 1) {
                    int row = 16 * wv + 4 * lhi + r;
                    int byte = (row * 256 + col * 2) ^ ((row & 7) << 4);
                    *(unsigned short*)((char*)xs + byte) = f2b(v);
                }
            }
        }
    }

    // ---- pass 2 (MODE 1): h' = relu(x' @ Wnt + bias_n) ----
    if (MODE == 1) {
        __syncthreads();
#pragma unroll
        for (int t = 0; t < 8; ++t) acc[t] = (f32x4)(0.f);
        bf16x8 afrag[4];
#pragma unroll
        for (int kk = 0; kk < 4; ++kk) {
            int byte = (arow * 256 + (kk * 32 + lhi * 8) * 2) ^ ((arow & 7) << 4);
            afrag[kk] = *(const bf16x8*)((const char*)xs + byte);
        }
#pragma unroll
        for (int nt = 0; nt < 8; ++nt) {
            const int ncol = nt * 16 + l15;
#pragma unroll
            for (int kk = 0; kk < 4; ++kk) {
                bf16x8 bfrag = *(const bf16x8*)(Wnt + (size_t)ncol * FEAT + kk * 32 + lhi * 8);
                acc[nt] = __builtin_amdgcn_mfma_f32_16x16x32_bf16(afrag[kk], bfrag, acc[nt], 0, 0, 0);
            }
        }
#pragma unroll
        for (int nt = 0; nt < 8; ++nt) {
            const int col = nt * 16 + l15;
            const float bv = bias_n[col];
#pragma unroll
            for (int r = 0; r < 4; ++r) {
                int n = rbase + r;
                if (n < N_NODES)
                    yh[(size_t)n * FEAT + col] = f2b(fmaxf(acc[nt][r] + bv, 0.f));
            }
        }
    }
}

// ---------------- segment max, 32-feat slices ----------------
// grid (25000, 4); 4 waves/block, 1 node/wave; quarter-wave (16 lanes) per edge:
// each quarter reads one 64B line (32 bf16 feats at f0 = blockIdx.y*32).
__global__ __launch_bounds__(256) void seg_max_kernel(
    const unsigned short* __restrict__ h_pool, const int* __restrict__ row_ptr,
    const int* __restrict__ edge_src, unsigned short* __restrict__ pooled) {
    const int node = blockIdx.x * 4 + (threadIdx.x >> 6);
    const int lane = threadIdx.x & 63;
    const int q = lane >> 4;     // quarter-wave: edge offset 0..3
    const int fl = lane & 15;    // 16 lanes x 2 feats = 32 feats
    const int f0 = blockIdx.y * 32;
    if (node >= N_NODES) return;
    const int start = row_ptr[node];
    const int end = row_ptr[node + 1];
    float ax = 0.f, ay = 0.f, bx = 0.f, by = 0.f;
    int i = start + q;
    for (; i + 4 < end; i += 8) {
        unsigned int v0 = *(const unsigned int*)(h_pool + (size_t)edge_src[i] * FEAT + f0 + fl * 2);
        unsigned int v1 = *(const unsigned int*)(h_pool + (size_t)edge_src[i + 4] * FEAT + f0 + fl * 2);
        ax = fmaxf(ax, __uint_as_float(v0 << 16));
        ay = fmaxf(ay, __uint_as_float(v0 & 0xffff0000u));
        bx = fmaxf(bx, __uint_as_float(v1 << 16));
        by = fmaxf(by, __uint_as_float(v1 & 0xffff0000u));
    }
    if (i < end) {
        unsigned int v0 = *(const unsigned int*)(h_pool + (size_t)edge_src[i] * FEAT + f0 + fl * 2);
        ax = fmaxf(ax, __uint_as_float(v0 << 16));
        ay = fmaxf(ay, __uint_as_float(v0 & 0xffff0000u));
    }
    float rx = fmaxf(ax, bx);
    float ry = fmaxf(ay, by);
    rx = fmaxf(rx, __shfl_xor(rx, 16, 64));
    ry = fmaxf(ry, __shfl_xor(ry, 16, 64));
    rx = fmaxf(rx, __shfl_xor(rx, 32, 64));
    ry = fmaxf(ry, __shfl_xor(ry, 32, 64));
    if (q == 0) {
        unsigned int o = (__float_as_uint(rx) >> 16) | (__float_as_uint(ry) & 0xffff0000u);
        *(unsigned int*)(pooled + (size_t)node * FEAT + f0 + fl * 2) = o;
    }
}

// ---------------- launch ----------------
// ws (~123 MB < proven 161): edge_src 6.4 | ebuf 12.8 | deg+bkt_cnt 0.4 |
// row_ptr 0.4 | blk_sums/bkt_start/bkt_cursor ~4KB | wt 0.39 | bufH 25.6 |
// bufP 25.6 | bufA 51.2

extern "C" void kernel_launch(void* const* d_in, const int* in_sizes, int n_in,
                              void* d_out, int out_size, void* d_ws, size_t ws_size,
                              hipStream_t stream) {
    const float* feats = (const float*)d_in[0];
    const float* Wp = (const float*)d_in[1];
    const float* bp = (const float*)d_in[2];
    const float* Ws = (const float*)d_in[3];
    const float* Wn = (const float*)d_in[4];
    const float* bb = (const float*)d_in[5];
    const int* src = (const int*)d_in[6];
    const int* dst = (const int*)d_in[7];
    float* out = (float*)d_out;

    const size_t NF = (size_t)N_NODES * FEAT;
    char* ws = (char*)d_ws;
    int* edge_src = (int*)ws;    ws += (size_t)N_EDGES * sizeof(int);
    int2* ebuf = (int2*)ws;      ws += (size_t)N_EDGES * sizeof(int2);
    int* deg = (int*)ws;         ws += (size_t)N_NODES * sizeof(int);
    int* bkt_cnt = (int*)ws;     ws += 256 * sizeof(int);
    int* row_ptr = (int*)ws;     ws += (size_t)(N_NODES + 4) * sizeof(int);
    int* blk_sums = (int*)ws;    ws += 512 * sizeof(int);
    int* bkt_start = (int*)ws;   ws += 256 * sizeof(int);
    int* bkt_cursor = (int*)ws;  ws += 256 * sizeof(int);
    unsigned short* wt = (unsigned short*)ws; ws += (size_t)12 * 16384 * sizeof(unsigned short);
    unsigned short* bufH = (unsigned short*)ws; ws += NF * sizeof(unsigned short);
    unsigned short* bufP = (unsigned short*)ws; ws += NF * sizeof(unsigned short);
    float* bufA = (float*)ws;

    // CSR build (deg & bkt_cnt adjacent -> single memset)
    hipMemsetAsync(deg, 0, ((size_t)N_NODES + 256) * sizeof(int), stream);
    count_deg_kernel<<<N_P1_BLKS, 256, 0, stream>>>(dst, deg, bkt_cnt);
    blk_sum_kernel<<<N_SCAN_BLKS, SCAN_BLK, 0, stream>>>(deg, blk_sums);
    scan_all_kernel<<<1, 512, 0, stream>>>(blk_sums, bkt_cnt, bkt_start, bkt_cursor);
    write_rowptr_kernel<<<N_SCAN_BLKS, SCAN_BLK, 0, stream>>>(deg, blk_sums, row_ptr);
    bucket_scatter_kernel<<<N_P1_BLKS, 256, 0, stream>>>(src, dst, bkt_cursor, ebuf);
    csr_scatter_kernel<<<NBKT, 256, 0, stream>>>(ebuf, bkt_start, row_ptr, edge_src);
    convert_wt_kernel<<<48, 256, 0, stream>>>(Wp, Ws, Wn, wt);

    const int gemm_grid = (N_NODES + 63) / 64;       // 1563
    const dim3 seg_grid((N_NODES + 3) / 4, 4);       // 25000 x 4 feature slices

    const float* x_in[LAYERS] = {feats, bufA, out, bufA};
    float* x_out[LAYERS] = {bufA, out, bufA, out};

    // layer 0 h_pool
    gemm_kernel<0><<<gemm_grid, 256, 0, stream>>>(
        feats, nullptr, wt + 0 * 16384, nullptr, bp, nullptr, nullptr, nullptr, bufH);

    for (int l = 0; l < LAYERS; ++l) {
        const unsigned short* WsT = wt + (size_t)(4 + l) * 16384;
        const unsigned short* WnT = wt + (size_t)(8 + l) * 16384;
        const float* bl = bb + (size_t)l * FEAT;

        seg_max_kernel<<<seg_grid, 256, 0, stream>>>(bufH, row_ptr, edge_src, bufP);

        if (l < LAYERS - 1) {
            const unsigned short* WpTn = wt + (size_t)(l + 1) * 16384;
            const float* bpn = bp + (size_t)(l + 1) * FEAT;
            gemm_kernel<1><<<gemm_grid, 256, 0, stream>>>(
                x_in[l], bufP, WsT, WnT, bl, WpTn, bpn, x_out[l], bufH);
        } else {
            gemm_kernel<2><<<gemm_grid, 256, 0, stream>>>(
                x_in[l], bufP, WsT, WnT, bl, nullptr, nullptr, x_out[l], nullptr);
        }
    }
}

// Round 6
// 1249.123 us; speedup vs baseline: 1.0181x; 1.0181x over previous
//
#include <hip/hip_runtime.h>

#define N_NODES 100000
#define N_EDGES 1600000
#define FEAT 128
#define LAYERS 4
#define SCAN_BLK 256
#define N_SCAN_BLKS ((N_NODES + SCAN_BLK - 1) / SCAN_BLK)  // 391

typedef __attribute__((ext_vector_type(8))) short bf16x8;
typedef __attribute__((ext_vector_type(4))) float f32x4;

__device__ __forceinline__ unsigned short f2b(float f) {   // f32 -> bf16 RNE
    union { float f; unsigned int u; } v; v.f = f;
    unsigned int u = v.u;
    return (unsigned short)((u + 0x7fffu + ((u >> 16) & 1u)) >> 16);
}

// ---------------- CSR build (R4-proven path) ----------------

__global__ void count_deg_kernel(const int* __restrict__ dst, int* __restrict__ deg) {
    int e = blockIdx.x * blockDim.x + threadIdx.x;
    if (e < N_EDGES) atomicAdd(&deg[dst[e]], 1);
}

__global__ __launch_bounds__(SCAN_BLK) void blk_sum_kernel(const int* __restrict__ deg,
                                                           int* __restrict__ blk_sums) {
    int i = blockIdx.x * SCAN_BLK + threadIdx.x;
    int v = (i < N_NODES) ? deg[i] : 0;
#pragma unroll
    for (int off = 32; off; off >>= 1) v += __shfl_down(v, off, 64);
    __shared__ int ws_[SCAN_BLK / 64];
    if ((threadIdx.x & 63) == 0) ws_[threadIdx.x >> 6] = v;
    __syncthreads();
    if (threadIdx.x == 0) {
        int s = 0;
#pragma unroll
        for (int w = 0; w < SCAN_BLK / 64; ++w) s += ws_[w];
        blk_sums[blockIdx.x] = s;
    }
}

__global__ __launch_bounds__(512) void scan_blk_kernel(int* __restrict__ blk_sums) {
    __shared__ int s[512];
    const int t = threadIdx.x;
    s[t] = (t < N_SCAN_BLKS) ? blk_sums[t] : 0;
    __syncthreads();
    for (int off = 1; off < 512; off <<= 1) {
        int v = (t >= off) ? s[t - off] : 0;
        __syncthreads();
        s[t] += v;
        __syncthreads();
    }
    if (t < N_SCAN_BLKS) blk_sums[t] = (t == 0) ? 0 : s[t - 1];
}

__global__ __launch_bounds__(SCAN_BLK) void write_rowptr_kernel(
    const int* __restrict__ deg, const int* __restrict__ blk_off,
    int* __restrict__ row_ptr, int* __restrict__ cursor) {
    __shared__ int s[SCAN_BLK];
    const int t = threadIdx.x;
    const int i = blockIdx.x * SCAN_BLK + t;
    int v = (i < N_NODES) ? deg[i] : 0;
    s[t] = v;
    __syncthreads();
    for (int off = 1; off < SCAN_BLK; off <<= 1) {
        int u = (t >= off) ? s[t - off] : 0;
        __syncthreads();
        s[t] += u;
        __syncthreads();
    }
    int excl = s[t] - v + blk_off[blockIdx.x];
    if (i < N_NODES) {
        row_ptr[i] = excl;
        cursor[i] = excl;
    }
    if (i == 0) row_ptr[N_NODES] = N_EDGES;
}

__global__ void fill_edges_kernel(const int* __restrict__ src, const int* __restrict__ dst,
                                  int* __restrict__ cursor, int* __restrict__ edge_src) {
    int e = blockIdx.x * blockDim.x + threadIdx.x;
    if (e < N_EDGES) {
        int pos = atomicAdd(&cursor[dst[e]], 1);
        edge_src[pos] = src[e];
    }
}

// ---------------- weight convert: Wt[m][n][k] = bf16(W[m][k][n]) ----------------
__global__ __launch_bounds__(256) void convert_wt_kernel(
    const float* __restrict__ Wp, const float* __restrict__ Ws,
    const float* __restrict__ Wn, unsigned short* __restrict__ wt) {
    __shared__ float tile[64][65];
    const int m = blockIdx.x >> 2;
    const int tij = blockIdx.x & 3;
    const int ti = tij >> 1, tj = tij & 1;
    const float* W = (m < 4) ? Wp + (size_t)m * 16384
                   : (m < 8) ? Ws + (size_t)(m - 4) * 16384
                             : Wn + (size_t)(m - 8) * 16384;
#pragma unroll
    for (int i = 0; i < 16; ++i) {
        int e = i * 256 + threadIdx.x;
        int r = e >> 6, c = e & 63;
        tile[r][c] = W[(size_t)(ti * 64 + r) * 128 + tj * 64 + c];
    }
    __syncthreads();
#pragma unroll
    for (int i = 0; i < 16; ++i) {
        int e = i * 256 + threadIdx.x;
        int r = e >> 6, c = e & 63;
        wt[(size_t)m * 16384 + (size_t)(tj * 64 + r) * 128 + ti * 64 + c] = f2b(tile[c][r]);
    }
}

// ---------------- MFMA GEMM ----------------
// MODE 0: yh = bf16(relu(x@W1+bias)), SLICE-MAJOR: yh[(nt*N + n)*16 + l15]
// MODE 1: yh = bf16(relu(x@W1 + p@W2 + bias)), row-major  (x' for next layer)
// MODE 2: yf = f32 (relu(x@W1 + p@W2 + bias)), row-major  (final out)
// AF32: x is f32 (layer 0 feats); else x is bf16 row-major.
template <int MODE, bool AF32>
__global__ __launch_bounds__(256) void gemm_kernel(
    const void* __restrict__ xv, const unsigned short* __restrict__ p,
    const unsigned short* __restrict__ W1t, const unsigned short* __restrict__ W2t,
    const float* __restrict__ bias, float* __restrict__ yf,
    unsigned short* __restrict__ yh) {
    __shared__ unsigned short xs[64 * FEAT];  // 16 KB, XOR-swizzled
    const int tid = threadIdx.x;
    const int wv = tid >> 6;
    const int lane = tid & 63;
    const int l15 = lane & 15;
    const int lhi = lane >> 4;
    const int n0 = blockIdx.x * 64;
    const int arow = 16 * wv + l15;
    const int rbase = n0 + 16 * wv + 4 * lhi;

    f32x4 acc[8];
#pragma unroll
    for (int t = 0; t < 8; ++t) acc[t] = (f32x4)(0.f);

    const int npass = (MODE >= 1) ? 2 : 1;
    for (int pass = 0; pass < npass; ++pass) {
        __syncthreads();
        if (pass == 0 && AF32) {
            const float* x = (const float*)xv;
#pragma unroll
            for (int i = 0; i < 4; ++i) {
                int chunk = i * 256 + tid;
                int row = chunk >> 4, c8 = chunk & 15;
                int n = n0 + row;
                float4 v0 = make_float4(0.f, 0.f, 0.f, 0.f), v1 = v0;
                if (n < N_NODES) {
                    const float4* g = (const float4*)(x + (size_t)n * FEAT + c8 * 8);
                    v0 = g[0]; v1 = g[1];
                }
                unsigned short hh[8];
                hh[0] = f2b(v0.x); hh[1] = f2b(v0.y); hh[2] = f2b(v0.z); hh[3] = f2b(v0.w);
                hh[4] = f2b(v1.x); hh[5] = f2b(v1.y); hh[6] = f2b(v1.z); hh[7] = f2b(v1.w);
                int byte = (row * 256 + c8 * 16) ^ ((row & 7) << 4);
                *(bf16x8*)((char*)xs + byte) = *(bf16x8*)hh;
            }
        } else {
            const unsigned short* srcb = pass ? p : (const unsigned short*)xv;
#pragma unroll
            for (int i = 0; i < 4; ++i) {
                int chunk = i * 256 + tid;
                int row = chunk >> 4, c8 = chunk & 15;
                int n = n0 + row;
                float4 v = make_float4(0.f, 0.f, 0.f, 0.f);
                if (n < N_NODES) v = *(const float4*)(srcb + (size_t)n * FEAT + c8 * 8);
                int byte = (row * 256 + c8 * 16) ^ ((row & 7) << 4);
                *(float4*)((char*)xs + byte) = v;
            }
        }
        __syncthreads();

        const unsigned short* Wt = pass ? W2t : W1t;
        bf16x8 afrag[4];
#pragma unroll
        for (int kk = 0; kk < 4; ++kk) {
            int byte = (arow * 256 + (kk * 32 + lhi * 8) * 2) ^ ((arow & 7) << 4);
            afrag[kk] = *(const bf16x8*)((const char*)xs + byte);
        }
#pragma unroll
        for (int nt = 0; nt < 8; ++nt) {
            const int ncol = nt * 16 + l15;
#pragma unroll
            for (int kk = 0; kk < 4; ++kk) {
                bf16x8 bfrag = *(const bf16x8*)(Wt + (size_t)ncol * FEAT + kk * 32 + lhi * 8);
                acc[nt] = __builtin_amdgcn_mfma_f32_16x16x32_bf16(afrag[kk], bfrag, acc[nt], 0, 0, 0);
            }
        }
    }

    // epilogue: row = rbase + r, col = nt*16 + l15
#pragma unroll
    for (int nt = 0; nt < 8; ++nt) {
        const int col = nt * 16 + l15;
        const float bv = bias[col];
#pragma unroll
        for (int r = 0; r < 4; ++r) {
            int n = rbase + r;
            if (n < N_NODES) {
                float v = fmaxf(acc[nt][r] + bv, 0.f);
                if (MODE == 0)      yh[((size_t)nt * N_NODES + n) * 16 + l15] = f2b(v);
                else if (MODE == 1) yh[(size_t)n * FEAT + col] = f2b(v);
                else                yf[(size_t)n * FEAT + col] = v;
            }
        }
    }
}

// ---------------- segment max, XCD-pinned feature slices ----------------
// h_pool SLICE-MAJOR: hs[s][node][16 feats] bf16; slice = 3.2 MB -> fits 4 MB L2.
// Grid 1-D, 25000 blocks; slice = blockIdx.x % 8 so round-robin dispatch pins
// slice s to XCD s. Block = 4 waves x 8 nodes; wave: 8 edge-slots x 8 feat-lanes.
__global__ __launch_bounds__(256) void seg_max_kernel(
    const unsigned short* __restrict__ hs, const int* __restrict__ row_ptr,
    const int* __restrict__ edge_src, unsigned short* __restrict__ pooled) {
    const int s = blockIdx.x & 7;
    const int g = blockIdx.x >> 3;          // 0..3124
    const int wv = threadIdx.x >> 6;
    const int lane = threadIdx.x & 63;
    const int e8 = lane >> 3;               // edge slot 0..7
    const int f = lane & 7;                 // feat pair 0..7 (16 feats)
    const unsigned short* hbase = hs + (size_t)s * N_NODES * 16;

#pragma unroll
    for (int j = 0; j < 8; ++j) {
        const int node = g * 32 + wv * 8 + j;
        if (node >= N_NODES) break;  // wave-uniform
        const int start = row_ptr[node];
        const int end = row_ptr[node + 1];
        float ax = 0.f, ay = 0.f, bx = 0.f, by = 0.f;
        int i = start + e8;
        for (; i + 8 < end; i += 16) {
            int s0 = edge_src[i];
            int s1 = edge_src[i + 8];
            unsigned int v0 = *(const unsigned int*)(hbase + (size_t)s0 * 16 + f * 2);
            unsigned int v1 = *(const unsigned int*)(hbase + (size_t)s1 * 16 + f * 2);
            ax = fmaxf(ax, __uint_as_float(v0 << 16));
            ay = fmaxf(ay, __uint_as_float(v0 & 0xffff0000u));
            bx = fmaxf(bx, __uint_as_float(v1 << 16));
            by = fmaxf(by, __uint_as_float(v1 & 0xffff0000u));
        }
        if (i < end) {
            unsigned int v0 = *(const unsigned int*)(hbase + (size_t)edge_src[i] * 16 + f * 2);
            ax = fmaxf(ax, __uint_as_float(v0 << 16));
            ay = fmaxf(ay, __uint_as_float(v0 & 0xffff0000u));
        }
        ax = fmaxf(ax, bx);
        ay = fmaxf(ay, by);
#pragma unroll
        for (int off = 8; off < 64; off <<= 1) {
            ax = fmaxf(ax, __shfl_xor(ax, off, 64));
            ay = fmaxf(ay, __shfl_xor(ay, off, 64));
        }
        if (lane < 8) {
            unsigned int o = (__float_as_uint(ax) >> 16) | (__float_as_uint(ay) & 0xffff0000u);
            __builtin_nontemporal_store(o,
                (unsigned int*)(pooled + (size_t)node * FEAT + s * 16 + f * 2));
        }
    }
}

// ---------------- launch ----------------
// ws (~112 MB < proven 161): edge_src 6.4 | deg 0.4 | row_ptr 0.4 | cursor 0.4 |
// blk_sums 2K | wt 0.39 | bufH 25.6 (slice-major) | bufP 25.6 (row-major) |
// bufX0 25.6 | bufX1 25.6 (bf16 x-chain pings)
// x chain: feats(f32) -> X0 -> X1 -> X0 -> d_out(f32)

extern "C" void kernel_launch(void* const* d_in, const int* in_sizes, int n_in,
                              void* d_out, int out_size, void* d_ws, size_t ws_size,
                              hipStream_t stream) {
    const float* feats = (const float*)d_in[0];
    const float* Wp = (const float*)d_in[1];
    const float* bp = (const float*)d_in[2];
    const float* Ws = (const float*)d_in[3];
    const float* Wn = (const float*)d_in[4];
    const float* bb = (const float*)d_in[5];
    const int* src = (const int*)d_in[6];
    const int* dst = (const int*)d_in[7];
    float* out = (float*)d_out;

    const size_t NF = (size_t)N_NODES * FEAT;
    char* ws = (char*)d_ws;
    int* edge_src = (int*)ws;    ws += (size_t)N_EDGES * sizeof(int);
    int* deg = (int*)ws;         ws += (size_t)N_NODES * sizeof(int);
    int* row_ptr = (int*)ws;     ws += (size_t)(N_NODES + 4) * sizeof(int);
    int* cursor = (int*)ws;      ws += (size_t)N_NODES * sizeof(int);
    int* blk_sums = (int*)ws;    ws += 512 * sizeof(int);
    unsigned short* wt = (unsigned short*)ws;   ws += (size_t)12 * 16384 * sizeof(unsigned short);
    unsigned short* bufH = (unsigned short*)ws; ws += NF * sizeof(unsigned short);
    unsigned short* bufP = (unsigned short*)ws; ws += NF * sizeof(unsigned short);
    unsigned short* bufX0 = (unsigned short*)ws; ws += NF * sizeof(unsigned short);
    unsigned short* bufX1 = (unsigned short*)ws;

    // CSR build (graph static across layers)
    hipMemsetAsync(deg, 0, (size_t)N_NODES * sizeof(int), stream);
    count_deg_kernel<<<(N_EDGES + 255) / 256, 256, 0, stream>>>(dst, deg);
    blk_sum_kernel<<<N_SCAN_BLKS, SCAN_BLK, 0, stream>>>(deg, blk_sums);
    scan_blk_kernel<<<1, 512, 0, stream>>>(blk_sums);
    write_rowptr_kernel<<<N_SCAN_BLKS, SCAN_BLK, 0, stream>>>(deg, blk_sums, row_ptr, cursor);
    fill_edges_kernel<<<(N_EDGES + 255) / 256, 256, 0, stream>>>(src, dst, cursor, edge_src);
    convert_wt_kernel<<<48, 256, 0, stream>>>(Wp, Ws, Wn, wt);

    const int gemm_grid = (N_NODES + 63) / 64;        // 1563
    const int seg_grid = ((N_NODES + 31) / 32) * 8;   // 3125 groups x 8 slices = 25000

    const unsigned short* xb[LAYERS] = {nullptr, bufX0, bufX1, bufX0};
    unsigned short* xo[LAYERS] = {bufX0, bufX1, bufX0, nullptr};

    for (int l = 0; l < LAYERS; ++l) {
        const unsigned short* WpT = wt + (size_t)l * 16384;
        const unsigned short* WsT = wt + (size_t)(4 + l) * 16384;
        const unsigned short* WnT = wt + (size_t)(8 + l) * 16384;
        const float* bpl = bp + (size_t)l * FEAT;
        const float* bl = bb + (size_t)l * FEAT;

        if (l == 0)
            gemm_kernel<0, true><<<gemm_grid, 256, 0, stream>>>(
                feats, nullptr, WpT, nullptr, bpl, nullptr, bufH);
        else
            gemm_kernel<0, false><<<gemm_grid, 256, 0, stream>>>(
                xb[l], nullptr, WpT, nullptr, bpl, nullptr, bufH);

        seg_max_kernel<<<seg_grid, 256, 0, stream>>>(bufH, row_ptr, edge_src, bufP);

        if (l == 0)
            gemm_kernel<1, true><<<gemm_grid, 256, 0, stream>>>(
                feats, bufP, WsT, WnT, bl, nullptr, xo[l]);
        else if (l < LAYERS - 1)
            gemm_kernel<1, false><<<gemm_grid, 256, 0, stream>>>(
                xb[l], bufP, WsT, WnT, bl, nullptr, xo[l]);
        else
            gemm_kernel<2, false><<<gemm_grid, 256, 0, stream>>>(
                xb[l], bufP, WsT, WnT, bl, out, nullptr);
    }
}

// Round 7
// 928.833 us; speedup vs baseline: 1.3692x; 1.3448x over previous
//
#include <hip/hip_runtime.h>

#define N_NODES 100000
#define N_EDGES 1600000
#define FEAT 128
#define LAYERS 4
#define SCAN_BLK 256
#define N_SCAN_BLKS ((N_NODES + SCAN_BLK - 1) / SCAN_BLK)  // 391
#define NBKT ((N_NODES + 511) >> 9)                        // 196 buckets x 512 nodes
#define P1_CHUNK 4096
#define N_P1_BLKS ((N_EDGES + P1_CHUNK - 1) / P1_CHUNK)    // 391

typedef __attribute__((ext_vector_type(8))) short bf16x8;
typedef __attribute__((ext_vector_type(4))) float f32x4;

__device__ __forceinline__ unsigned short f2b(float f) {   // f32 -> bf16 RNE
    union { float f; unsigned int u; } v; v.f = f;
    unsigned int u = v.u;
    return (unsigned short)((u + 0x7fffu + ((u >> 16) & 1u)) >> 16);
}

// packed max of 2x bf16 (valid for non-negative bf16: bit pattern is monotone)
__device__ __forceinline__ unsigned int pkmax(unsigned int a, unsigned int b) {
    unsigned int r;
    asm("v_pk_max_u16 %0, %1, %2" : "=v"(r) : "v"(a), "v"(b));
    return r;
}

// ---------------- CSR build (bucketed, R5-proven) ----------------

__global__ __launch_bounds__(256) void count_deg_kernel(const int* __restrict__ dst,
                                                        int* __restrict__ deg,
                                                        int* __restrict__ bkt_cnt) {
    __shared__ int h[NBKT];
    for (int i = threadIdx.x; i < NBKT; i += 256) h[i] = 0;
    __syncthreads();
    const int base = blockIdx.x * P1_CHUNK;
    for (int i = threadIdx.x; i < P1_CHUNK; i += 256) {
        int e = base + i;
        if (e < N_EDGES) {
            int d = dst[e];
            atomicAdd(&deg[d], 1);
            atomicAdd(&h[d >> 9], 1);
        }
    }
    __syncthreads();
    for (int i = threadIdx.x; i < NBKT; i += 256)
        if (h[i]) atomicAdd(&bkt_cnt[i], h[i]);
}

__global__ __launch_bounds__(SCAN_BLK) void blk_sum_kernel(const int* __restrict__ deg,
                                                           int* __restrict__ blk_sums) {
    int i = blockIdx.x * SCAN_BLK + threadIdx.x;
    int v = (i < N_NODES) ? deg[i] : 0;
#pragma unroll
    for (int off = 32; off; off >>= 1) v += __shfl_down(v, off, 64);
    __shared__ int ws_[SCAN_BLK / 64];
    if ((threadIdx.x & 63) == 0) ws_[threadIdx.x >> 6] = v;
    __syncthreads();
    if (threadIdx.x == 0) {
        int s = 0;
#pragma unroll
        for (int w = 0; w < SCAN_BLK / 64; ++w) s += ws_[w];
        blk_sums[blockIdx.x] = s;
    }
}

__global__ __launch_bounds__(512) void scan_all_kernel(int* __restrict__ blk_sums,
                                                       const int* __restrict__ bkt_cnt,
                                                       int* __restrict__ bkt_start,
                                                       int* __restrict__ bkt_cursor) {
    __shared__ int s[512];
    __shared__ int b[256];
    const int t = threadIdx.x;
    s[t] = (t < N_SCAN_BLKS) ? blk_sums[t] : 0;
    if (t < 256) b[t] = (t < NBKT) ? bkt_cnt[t] : 0;
    __syncthreads();
    for (int off = 1; off < 512; off <<= 1) {
        int v = (t >= off) ? s[t - off] : 0;
        __syncthreads();
        s[t] += v;
        __syncthreads();
    }
    for (int off = 1; off < 256; off <<= 1) {
        int v = (t < 256 && t >= off) ? b[t - off] : 0;
        __syncthreads();
        if (t < 256) b[t] += v;
        __syncthreads();
    }
    if (t < N_SCAN_BLKS) blk_sums[t] = (t == 0) ? 0 : s[t - 1];
    if (t < NBKT) {
        int st = (t == 0) ? 0 : b[t - 1];
        bkt_start[t] = st;
        bkt_cursor[t] = st;
    }
    if (t == 0) bkt_start[NBKT] = N_EDGES;
}

__global__ __launch_bounds__(SCAN_BLK) void write_rowptr_kernel(
    const int* __restrict__ deg, const int* __restrict__ blk_off,
    int* __restrict__ row_ptr) {
    __shared__ int s[SCAN_BLK];
    const int t = threadIdx.x;
    const int i = blockIdx.x * SCAN_BLK + t;
    int v = (i < N_NODES) ? deg[i] : 0;
    s[t] = v;
    __syncthreads();
    for (int off = 1; off < SCAN_BLK; off <<= 1) {
        int u = (t >= off) ? s[t - off] : 0;
        __syncthreads();
        s[t] += u;
        __syncthreads();
    }
    int excl = s[t] - v + blk_off[blockIdx.x];
    if (i < N_NODES) row_ptr[i] = excl;
    if (i == 0) row_ptr[N_NODES] = N_EDGES;
}

__global__ __launch_bounds__(256) void bucket_scatter_kernel(
    const int* __restrict__ src, const int* __restrict__ dst,
    int* __restrict__ bkt_cursor, int2* __restrict__ ebuf) {
    __shared__ int h[NBKT], base[NBKT], cur[NBKT];
    for (int i = threadIdx.x; i < NBKT; i += 256) h[i] = 0;
    __syncthreads();
    const int b0 = blockIdx.x * P1_CHUNK;
    for (int i = threadIdx.x; i < P1_CHUNK; i += 256) {
        int e = b0 + i;
        if (e < N_EDGES) atomicAdd(&h[dst[e] >> 9], 1);
    }
    __syncthreads();
    for (int i = threadIdx.x; i < NBKT; i += 256) {
        cur[i] = 0;
        base[i] = h[i] ? atomicAdd(&bkt_cursor[i], h[i]) : 0;
    }
    __syncthreads();
    for (int i = threadIdx.x; i < P1_CHUNK; i += 256) {
        int e = b0 + i;
        if (e < N_EDGES) {
            int d = dst[e];
            int bk = d >> 9;
            int pos = base[bk] + atomicAdd(&cur[bk], 1);
            ebuf[pos] = make_int2(src[e], d);
        }
    }
}

__global__ __launch_bounds__(256) void csr_scatter_kernel(
    const int2* __restrict__ ebuf, const int* __restrict__ bkt_start,
    const int* __restrict__ row_ptr, int* __restrict__ edge_src) {
    __shared__ int cur[512];
    const int bk = blockIdx.x;
    const int n0 = bk << 9;
    for (int i = threadIdx.x; i < 512; i += 256) {
        int n = n0 + i;
        cur[i] = (n < N_NODES) ? row_ptr[n] : 0;
    }
    __syncthreads();
    const int s = bkt_start[bk], e = bkt_start[bk + 1];
    for (int i = s + threadIdx.x; i < e; i += 256) {
        int2 ed = ebuf[i];
        int pos = atomicAdd(&cur[ed.y - n0], 1);
        edge_src[pos] = ed.x;
    }
}

// ---------------- weight convert: Wt[m][n][k] = bf16(W[m][k][n]) ----------------
__global__ __launch_bounds__(256) void convert_wt_kernel(
    const float* __restrict__ Wp, const float* __restrict__ Ws,
    const float* __restrict__ Wn, unsigned short* __restrict__ wt) {
    __shared__ float tile[64][65];
    const int m = blockIdx.x >> 2;
    const int tij = blockIdx.x & 3;
    const int ti = tij >> 1, tj = tij & 1;
    const float* W = (m < 4) ? Wp + (size_t)m * 16384
                   : (m < 8) ? Ws + (size_t)(m - 4) * 16384
                             : Wn + (size_t)(m - 8) * 16384;
#pragma unroll
    for (int i = 0; i < 16; ++i) {
        int e = i * 256 + threadIdx.x;
        int r = e >> 6, c = e & 63;
        tile[r][c] = W[(size_t)(ti * 64 + r) * 128 + tj * 64 + c];
    }
    __syncthreads();
#pragma unroll
    for (int i = 0; i < 16; ++i) {
        int e = i * 256 + threadIdx.x;
        int r = e >> 6, c = e & 63;
        wt[(size_t)m * 16384 + (size_t)(tj * 64 + r) * 128 + ti * 64 + c] = f2b(tile[c][r]);
    }
}

// ---------------- MFMA GEMM, fused modes ----------------
// MODE 0: h  = bf16(relu(x@W1+bias))              -> yh SLICE-MAJOR
// MODE 1: x' = relu(x@W1 + p@W2 + bias)           -> yx bf16 row-major
//         h' = bf16(relu(x'@Wnt + bias_n))        -> yh SLICE-MAJOR
// MODE 2: x' = relu(x@W1 + p@W2 + bias)           -> yf f32 row-major (final)
// slice-major: yh[((nt*N + n)*16 + l15]
template <int MODE, bool AF32>
__global__ __launch_bounds__(256) void gemm_kernel(
    const void* __restrict__ xv, const unsigned short* __restrict__ p,
    const unsigned short* __restrict__ W1t, const unsigned short* __restrict__ W2t,
    const float* __restrict__ bias,
    const unsigned short* __restrict__ Wnt, const float* __restrict__ bias_n,
    float* __restrict__ yf, unsigned short* __restrict__ yx,
    unsigned short* __restrict__ yh) {
    __shared__ unsigned short xs[64 * FEAT];  // 16 KB, XOR-swizzled
    const int tid = threadIdx.x;
    const int wv = tid >> 6;
    const int lane = tid & 63;
    const int l15 = lane & 15;
    const int lhi = lane >> 4;
    const int n0 = blockIdx.x * 64;
    const int arow = 16 * wv + l15;
    const int rbase = n0 + 16 * wv + 4 * lhi;

    f32x4 acc[8];
#pragma unroll
    for (int t = 0; t < 8; ++t) acc[t] = (f32x4)(0.f);

    const int npass = (MODE >= 1) ? 2 : 1;
    for (int pass = 0; pass < npass; ++pass) {
        __syncthreads();
        if (pass == 0 && AF32) {
            const float* x = (const float*)xv;
#pragma unroll
            for (int i = 0; i < 4; ++i) {
                int chunk = i * 256 + tid;
                int row = chunk >> 4, c8 = chunk & 15;
                int n = n0 + row;
                float4 v0 = make_float4(0.f, 0.f, 0.f, 0.f), v1 = v0;
                if (n < N_NODES) {
                    const float4* g = (const float4*)(x + (size_t)n * FEAT + c8 * 8);
                    v0 = g[0]; v1 = g[1];
                }
                unsigned short hh[8];
                hh[0] = f2b(v0.x); hh[1] = f2b(v0.y); hh[2] = f2b(v0.z); hh[3] = f2b(v0.w);
                hh[4] = f2b(v1.x); hh[5] = f2b(v1.y); hh[6] = f2b(v1.z); hh[7] = f2b(v1.w);
                int byte = (row * 256 + c8 * 16) ^ ((row & 7) << 4);
                *(bf16x8*)((char*)xs + byte) = *(bf16x8*)hh;
            }
        } else {
            const unsigned short* srcb = pass ? p : (const unsigned short*)xv;
#pragma unroll
            for (int i = 0; i < 4; ++i) {
                int chunk = i * 256 + tid;
                int row = chunk >> 4, c8 = chunk & 15;
                int n = n0 + row;
                float4 v = make_float4(0.f, 0.f, 0.f, 0.f);
                if (n < N_NODES) v = *(const float4*)(srcb + (size_t)n * FEAT + c8 * 8);
                int byte = (row * 256 + c8 * 16) ^ ((row & 7) << 4);
                *(float4*)((char*)xs + byte) = v;
            }
        }
        __syncthreads();

        const unsigned short* Wt = pass ? W2t : W1t;
        bf16x8 afrag[4];
#pragma unroll
        for (int kk = 0; kk < 4; ++kk) {
            int byte = (arow * 256 + (kk * 32 + lhi * 8) * 2) ^ ((arow & 7) << 4);
            afrag[kk] = *(const bf16x8*)((const char*)xs + byte);
        }
#pragma unroll
        for (int nt = 0; nt < 8; ++nt) {
            const int ncol = nt * 16 + l15;
#pragma unroll
            for (int kk = 0; kk < 4; ++kk) {
                bf16x8 bfrag = *(const bf16x8*)(Wt + (size_t)ncol * FEAT + kk * 32 + lhi * 8);
                acc[nt] = __builtin_amdgcn_mfma_f32_16x16x32_bf16(afrag[kk], bfrag, acc[nt], 0, 0, 0);
            }
        }
    }

    // epilogue 1: bias + relu, write primary output
    if (MODE == 1) __syncthreads();  // all xs reads done before overwrite
#pragma unroll
    for (int nt = 0; nt < 8; ++nt) {
        const int col = nt * 16 + l15;
        const float bv = bias[col];
#pragma unroll
        for (int r = 0; r < 4; ++r) {
            int n = rbase + r;
            float v = fmaxf(acc[nt][r] + bv, 0.f);
            if (n < N_NODES) {
                if (MODE == 0)      yh[((size_t)nt * N_NODES + n) * 16 + l15] = f2b(v);
                else if (MODE == 2) yf[(size_t)n * FEAT + col] = v;
                else                yx[(size_t)n * FEAT + col] = f2b(v);
            }
            if (MODE == 1) {
                int row = 16 * wv + 4 * lhi + r;
                int byte = (row * 256 + col * 2) ^ ((row & 7) << 4);
                *(unsigned short*)((char*)xs + byte) = f2b(v);
            }
        }
    }

    // pass 3 (MODE 1): h' = relu(x' @ Wnt + bias_n), slice-major
    if (MODE == 1) {
        __syncthreads();
#pragma unroll
        for (int t = 0; t < 8; ++t) acc[t] = (f32x4)(0.f);
        bf16x8 afrag[4];
#pragma unroll
        for (int kk = 0; kk < 4; ++kk) {
            int byte = (arow * 256 + (kk * 32 + lhi * 8) * 2) ^ ((arow & 7) << 4);
            afrag[kk] = *(const bf16x8*)((const char*)xs + byte);
        }
#pragma unroll
        for (int nt = 0; nt < 8; ++nt) {
            const int ncol = nt * 16 + l15;
#pragma unroll
            for (int kk = 0; kk < 4; ++kk) {
                bf16x8 bfrag = *(const bf16x8*)(Wnt + (size_t)ncol * FEAT + kk * 32 + lhi * 8);
                acc[nt] = __builtin_amdgcn_mfma_f32_16x16x32_bf16(afrag[kk], bfrag, acc[nt], 0, 0, 0);
            }
        }
#pragma unroll
        for (int nt = 0; nt < 8; ++nt) {
            const int col = nt * 16 + l15;
            const float bv = bias_n[col];
#pragma unroll
            for (int r = 0; r < 4; ++r) {
                int n = rbase + r;
                if (n < N_NODES)
                    yh[((size_t)nt * N_NODES + n) * 16 + l15] = f2b(fmaxf(acc[nt][r] + bv, 0.f));
            }
        }
    }
}

// ---------------- segment max, XCD-pinned slices, 4-node ILP ----------------
// h slice-major: hs[s][node][16 feats] bf16 (3.2 MB/slice -> one XCD L2).
// slice = blockIdx.x & 7 (round-robin XCD pin). Block = 4 waves x 4 nodes.
// Quarter-wave per node: 4 edge-slots x 4 feat-lanes (8B = 4 feats each).
__global__ __launch_bounds__(256) void seg_max_kernel(
    const unsigned short* __restrict__ hs, const int* __restrict__ row_ptr,
    const int* __restrict__ edge_src, unsigned short* __restrict__ pooled) {
    const int s = blockIdx.x & 7;
    const int g = blockIdx.x >> 3;            // node group of 16
    const int wv = threadIdx.x >> 6;
    const int lane = threadIdx.x & 63;
    const int qn = lane >> 4;                 // node-in-wave 0..3
    const int slot = (lane >> 2) & 3;         // edge slot 0..3
    const int f = lane & 3;                   // feat quad 0..3
    int node = g * 16 + wv * 4 + qn;
    const bool valid = node < N_NODES;
    node = valid ? node : N_NODES - 1;
    const unsigned short* hbase = hs + (size_t)s * N_NODES * 16;

    const int start = row_ptr[node];
    const int end = row_ptr[node + 1];
    unsigned int a0 = 0u, a1 = 0u;            // packed 4x bf16 (>=0)
    int i = start + slot;
    for (; i + 4 < end; i += 8) {
        const uint2 v0 = *(const uint2*)(hbase + (size_t)edge_src[i] * 16 + f * 4);
        const uint2 v1 = *(const uint2*)(hbase + (size_t)edge_src[i + 4] * 16 + f * 4);
        a0 = pkmax(a0, v0.x); a1 = pkmax(a1, v0.y);
        a0 = pkmax(a0, v1.x); a1 = pkmax(a1, v1.y);
    }
    if (i < end) {
        const uint2 v0 = *(const uint2*)(hbase + (size_t)edge_src[i] * 16 + f * 4);
        a0 = pkmax(a0, v0.x); a1 = pkmax(a1, v0.y);
    }
    // reduce across the 4 slots (lane bits 2..3)
    a0 = pkmax(a0, __shfl_xor(a0, 4, 64));
    a1 = pkmax(a1, __shfl_xor(a1, 4, 64));
    a0 = pkmax(a0, __shfl_xor(a0, 8, 64));
    a1 = pkmax(a1, __shfl_xor(a1, 8, 64));
    if (slot == 0 && valid) {
        *(uint2*)(pooled + (size_t)node * FEAT + s * 16 + f * 4) = make_uint2(a0, a1);
    }
}

// ---------------- launch ----------------
// ws (~148 MB < proven 161): edge_src 6.4 | ebuf 12.8 | deg 0.4 | bkt_cnt 1K |
// row_ptr 0.4 | blk_sums 2K | bkt_start 1K | bkt_cursor 1K | wt 0.39 |
// bufH 25.6 (slice-major) | bufP 25.6 | bufX0 25.6 | bufX1 25.6
// x chain: feats(f32) -> X0 -> X1 -> X0 -> d_out(f32)

extern "C" void kernel_launch(void* const* d_in, const int* in_sizes, int n_in,
                              void* d_out, int out_size, void* d_ws, size_t ws_size,
                              hipStream_t stream) {
    const float* feats = (const float*)d_in[0];
    const float* Wp = (const float*)d_in[1];
    const float* bp = (const float*)d_in[2];
    const float* Ws = (const float*)d_in[3];
    const float* Wn = (const float*)d_in[4];
    const float* bb = (const float*)d_in[5];
    const int* src = (const int*)d_in[6];
    const int* dst = (const int*)d_in[7];
    float* out = (float*)d_out;

    const size_t NF = (size_t)N_NODES * FEAT;
    char* ws = (char*)d_ws;
    int* edge_src = (int*)ws;    ws += (size_t)N_EDGES * sizeof(int);
    int2* ebuf = (int2*)ws;      ws += (size_t)N_EDGES * sizeof(int2);
    int* deg = (int*)ws;         ws += (size_t)N_NODES * sizeof(int);
    int* bkt_cnt = (int*)ws;     ws += 256 * sizeof(int);
    int* row_ptr = (int*)ws;     ws += (size_t)(N_NODES + 4) * sizeof(int);
    int* blk_sums = (int*)ws;    ws += 512 * sizeof(int);
    int* bkt_start = (int*)ws;   ws += 256 * sizeof(int);
    int* bkt_cursor = (int*)ws;  ws += 256 * sizeof(int);
    unsigned short* wt = (unsigned short*)ws;    ws += (size_t)12 * 16384 * sizeof(unsigned short);
    unsigned short* bufH = (unsigned short*)ws;  ws += NF * sizeof(unsigned short);
    unsigned short* bufP = (unsigned short*)ws;  ws += NF * sizeof(unsigned short);
    unsigned short* bufX0 = (unsigned short*)ws; ws += NF * sizeof(unsigned short);
    unsigned short* bufX1 = (unsigned short*)ws;

    // CSR build (deg & bkt_cnt adjacent -> single memset)
    hipMemsetAsync(deg, 0, ((size_t)N_NODES + 256) * sizeof(int), stream);
    count_deg_kernel<<<N_P1_BLKS, 256, 0, stream>>>(dst, deg, bkt_cnt);
    blk_sum_kernel<<<N_SCAN_BLKS, SCAN_BLK, 0, stream>>>(deg, blk_sums);
    scan_all_kernel<<<1, 512, 0, stream>>>(blk_sums, bkt_cnt, bkt_start, bkt_cursor);
    write_rowptr_kernel<<<N_SCAN_BLKS, SCAN_BLK, 0, stream>>>(deg, blk_sums, row_ptr);
    bucket_scatter_kernel<<<N_P1_BLKS, 256, 0, stream>>>(src, dst, bkt_cursor, ebuf);
    csr_scatter_kernel<<<NBKT, 256, 0, stream>>>(ebuf, bkt_start, row_ptr, edge_src);
    convert_wt_kernel<<<48, 256, 0, stream>>>(Wp, Ws, Wn, wt);

    const int gemm_grid = (N_NODES + 63) / 64;        // 1563
    const int seg_grid = ((N_NODES + 15) / 16) * 8;   // 6250 groups x 8 slices

    const unsigned short* xb[LAYERS] = {nullptr, bufX0, bufX1, bufX0};
    unsigned short* xo[LAYERS] = {bufX0, bufX1, bufX0, nullptr};

    // layer 0 h_pool
    gemm_kernel<0, true><<<gemm_grid, 256, 0, stream>>>(
        feats, nullptr, wt, nullptr, bp, nullptr, nullptr, nullptr, nullptr, bufH);

    for (int l = 0; l < LAYERS; ++l) {
        const unsigned short* WsT = wt + (size_t)(4 + l) * 16384;
        const unsigned short* WnT = wt + (size_t)(8 + l) * 16384;
        const float* bl = bb + (size_t)l * FEAT;

        seg_max_kernel<<<seg_grid, 256, 0, stream>>>(bufH, row_ptr, edge_src, bufP);

        if (l == 0) {
            gemm_kernel<1, true><<<gemm_grid, 256, 0, stream>>>(
                feats, bufP, WsT, WnT, bl, wt + (size_t)(l + 1) * 16384,
                bp + (size_t)(l + 1) * FEAT, nullptr, xo[l], bufH);
        } else if (l < LAYERS - 1) {
            gemm_kernel<1, false><<<gemm_grid, 256, 0, stream>>>(
                xb[l], bufP, WsT, WnT, bl, wt + (size_t)(l + 1) * 16384,
                bp + (size_t)(l + 1) * FEAT, nullptr, xo[l], bufH);
        } else {
            gemm_kernel<2, false><<<gemm_grid, 256, 0, stream>>>(
                xb[l], bufP, WsT, WnT, bl, nullptr, nullptr, out, nullptr, nullptr);
        }
    }
}

// Round 8
// 854.178 us; speedup vs baseline: 1.4888x; 1.0874x over previous
//
#include <hip/hip_runtime.h>

#define N_NODES 100000
#define N_EDGES 1600000
#define FEAT 128
#define LAYERS 4
#define SCAN_BLK 256
#define N_SCAN_BLKS ((N_NODES + SCAN_BLK - 1) / SCAN_BLK)  // 391
#define NBKT ((N_NODES + 511) >> 9)                        // 196 buckets x 512 nodes
#define P1_CHUNK 4096
#define N_P1_BLKS ((N_EDGES + P1_CHUNK - 1) / P1_CHUNK)    // 391

typedef __attribute__((ext_vector_type(8))) short bf16x8;
typedef __attribute__((ext_vector_type(4))) float f32x4;

__device__ __forceinline__ unsigned short f2b(float f) {   // f32 -> bf16 RNE
    union { float f; unsigned int u; } v; v.f = f;
    unsigned int u = v.u;
    return (unsigned short)((u + 0x7fffu + ((u >> 16) & 1u)) >> 16);
}

// packed max of 2x bf16 (valid for non-negative bf16: bit pattern is monotone)
__device__ __forceinline__ unsigned int pkmax(unsigned int a, unsigned int b) {
    unsigned int r;
    asm("v_pk_max_u16 %0, %1, %2" : "=v"(r) : "v"(a), "v"(b));
    return r;
}

// ---------------- CSR build (bucketed) ----------------

__global__ __launch_bounds__(256) void count_deg_kernel(const int* __restrict__ dst,
                                                        int* __restrict__ deg,
                                                        int* __restrict__ bkt_cnt) {
    __shared__ int h[NBKT];
    for (int i = threadIdx.x; i < NBKT; i += 256) h[i] = 0;
    __syncthreads();
    const int base = blockIdx.x * P1_CHUNK;
    for (int i = threadIdx.x; i < P1_CHUNK; i += 256) {
        int e = base + i;
        if (e < N_EDGES) {
            int d = dst[e];
            atomicAdd(&deg[d], 1);
            atomicAdd(&h[d >> 9], 1);
        }
    }
    __syncthreads();
    for (int i = threadIdx.x; i < NBKT; i += 256)
        if (h[i]) atomicAdd(&bkt_cnt[i], h[i]);
}

__global__ __launch_bounds__(SCAN_BLK) void blk_sum_kernel(const int* __restrict__ deg,
                                                           int* __restrict__ blk_sums) {
    int i = blockIdx.x * SCAN_BLK + threadIdx.x;
    int v = (i < N_NODES) ? deg[i] : 0;
#pragma unroll
    for (int off = 32; off; off >>= 1) v += __shfl_down(v, off, 64);
    __shared__ int ws_[SCAN_BLK / 64];
    if ((threadIdx.x & 63) == 0) ws_[threadIdx.x >> 6] = v;
    __syncthreads();
    if (threadIdx.x == 0) {
        int s = 0;
#pragma unroll
        for (int w = 0; w < SCAN_BLK / 64; ++w) s += ws_[w];
        blk_sums[blockIdx.x] = s;
    }
}

__global__ __launch_bounds__(512) void scan_all_kernel(int* __restrict__ blk_sums,
                                                       const int* __restrict__ bkt_cnt,
                                                       int* __restrict__ bkt_start,
                                                       int* __restrict__ bkt_cursor) {
    __shared__ int s[512];
    __shared__ int b[256];
    const int t = threadIdx.x;
    s[t] = (t < N_SCAN_BLKS) ? blk_sums[t] : 0;
    if (t < 256) b[t] = (t < NBKT) ? bkt_cnt[t] : 0;
    __syncthreads();
    for (int off = 1; off < 512; off <<= 1) {
        int v = (t >= off) ? s[t - off] : 0;
        __syncthreads();
        s[t] += v;
        __syncthreads();
    }
    for (int off = 1; off < 256; off <<= 1) {
        int v = (t < 256 && t >= off) ? b[t - off] : 0;
        __syncthreads();
        if (t < 256) b[t] += v;
        __syncthreads();
    }
    if (t < N_SCAN_BLKS) blk_sums[t] = (t == 0) ? 0 : s[t - 1];
    if (t < NBKT) {
        int st = (t == 0) ? 0 : b[t - 1];
        bkt_start[t] = st;
        bkt_cursor[t] = st;
    }
    if (t == 0) bkt_start[NBKT] = N_EDGES;
}

__global__ __launch_bounds__(SCAN_BLK) void write_rowptr_kernel(
    const int* __restrict__ deg, const int* __restrict__ blk_off,
    int* __restrict__ row_ptr) {
    __shared__ int s[SCAN_BLK];
    const int t = threadIdx.x;
    const int i = blockIdx.x * SCAN_BLK + t;
    int v = (i < N_NODES) ? deg[i] : 0;
    s[t] = v;
    __syncthreads();
    for (int off = 1; off < SCAN_BLK; off <<= 1) {
        int u = (t >= off) ? s[t - off] : 0;
        __syncthreads();
        s[t] += u;
        __syncthreads();
    }
    int excl = s[t] - v + blk_off[blockIdx.x];
    if (i < N_NODES) row_ptr[i] = excl;
    if (i == 0) row_ptr[N_NODES] = N_EDGES;
}

__global__ __launch_bounds__(256) void bucket_scatter_kernel(
    const int* __restrict__ src, const int* __restrict__ dst,
    int* __restrict__ bkt_cursor, int2* __restrict__ ebuf) {
    __shared__ int h[NBKT], base[NBKT], cur[NBKT];
    for (int i = threadIdx.x; i < NBKT; i += 256) h[i] = 0;
    __syncthreads();
    const int b0 = blockIdx.x * P1_CHUNK;
    for (int i = threadIdx.x; i < P1_CHUNK; i += 256) {
        int e = b0 + i;
        if (e < N_EDGES) atomicAdd(&h[dst[e] >> 9], 1);
    }
    __syncthreads();
    for (int i = threadIdx.x; i < NBKT; i += 256) {
        cur[i] = 0;
        base[i] = h[i] ? atomicAdd(&bkt_cursor[i], h[i]) : 0;
    }
    __syncthreads();
    for (int i = threadIdx.x; i < P1_CHUNK; i += 256) {
        int e = b0 + i;
        if (e < N_EDGES) {
            int d = dst[e];
            int bk = d >> 9;
            int pos = base[bk] + atomicAdd(&cur[bk], 1);
            ebuf[pos] = make_int2(src[e], d);
        }
    }
}

__global__ __launch_bounds__(256) void csr_scatter_kernel(
    const int2* __restrict__ ebuf, const int* __restrict__ bkt_start,
    const int* __restrict__ row_ptr, int* __restrict__ edge_src) {
    __shared__ int cur[512];
    const int bk = blockIdx.x;
    const int n0 = bk << 9;
    for (int i = threadIdx.x; i < 512; i += 256) {
        int n = n0 + i;
        cur[i] = (n < N_NODES) ? row_ptr[n] : 0;
    }
    __syncthreads();
    const int s = bkt_start[bk], e = bkt_start[bk + 1];
    for (int i = s + threadIdx.x; i < e; i += 256) {
        int2 ed = ebuf[i];
        int pos = atomicAdd(&cur[ed.y - n0], 1);
        edge_src[pos] = ed.x;
    }
}

// ---------------- weight convert: Wt[m][n][k] = bf16(W[m][k][n]) ----------------
__global__ __launch_bounds__(256) void convert_wt_kernel(
    const float* __restrict__ Wp, const float* __restrict__ Ws,
    const float* __restrict__ Wn, unsigned short* __restrict__ wt) {
    __shared__ float tile[64][65];
    const int m = blockIdx.x >> 2;
    const int tij = blockIdx.x & 3;
    const int ti = tij >> 1, tj = tij & 1;
    const float* W = (m < 4) ? Wp + (size_t)m * 16384
                   : (m < 8) ? Ws + (size_t)(m - 4) * 16384
                             : Wn + (size_t)(m - 8) * 16384;
#pragma unroll
    for (int i = 0; i < 16; ++i) {
        int e = i * 256 + threadIdx.x;
        int r = e >> 6, c = e & 63;
        tile[r][c] = W[(size_t)(ti * 64 + r) * 128 + tj * 64 + c];
    }
    __syncthreads();
#pragma unroll
    for (int i = 0; i < 16; ++i) {
        int e = i * 256 + threadIdx.x;
        int r = e >> 6, c = e & 63;
        wt[(size_t)m * 16384 + (size_t)(tj * 64 + r) * 128 + ti * 64 + c] = f2b(tile[c][r]);
    }
}

// ---------------- MFMA GEMM, swapped operands (A=Wt, B=x) ----------------
// D col = lane&15 -> NODE; D row = 4*(lane>>4)+reg -> 4 CONSECUTIVE FEATURES.
// So each lane owns one node and stores packed 8B/16B chunks (wide stores).
// MODE 0: h  = bf16(relu(x@W1+bias))           -> yh SLICE-MAJOR [ft][n][16]
// MODE 1: x' = relu(x@W1 + p@W2 + bias)        -> yx bf16 row-major
//         h' = bf16(relu(x'@Wnt + bias_n))     -> yh SLICE-MAJOR
// MODE 2: x' -> yf f32 row-major (final out)
// p input is SLICE-MAJOR [s][n][16].
template <int MODE, bool AF32>
__global__ __launch_bounds__(256, 3) void gemm_kernel(
    const void* __restrict__ xv, const unsigned short* __restrict__ p,
    const unsigned short* __restrict__ W1t, const unsigned short* __restrict__ W2t,
    const float* __restrict__ bias,
    const unsigned short* __restrict__ Wnt, const float* __restrict__ bias_n,
    float* __restrict__ yf, unsigned short* __restrict__ yx,
    unsigned short* __restrict__ yh) {
    __shared__ unsigned short xs[64 * FEAT];  // 16 KB, XOR-swizzled
    const int tid = threadIdx.x;
    const int wv = tid >> 6;
    const int lane = tid & 63;
    const int l15 = lane & 15;
    const int lhi = lane >> 4;
    const int n0 = blockIdx.x * 64;
    const int nrow = 16 * wv + l15;     // node-in-block this lane owns (B col)
    const int nglob = n0 + nrow;
    const int fsub = 4 * lhi;           // feature sub-offset within 16-tile (D rows)

    f32x4 acc[8];
#pragma unroll
    for (int t = 0; t < 8; ++t) acc[t] = (f32x4)(0.f);

    const int npass = (MODE >= 1) ? 2 : 1;
    for (int pass = 0; pass < npass; ++pass) {
        __syncthreads();
        if (pass == 0 && AF32) {
            const float* x = (const float*)xv;
#pragma unroll
            for (int i = 0; i < 4; ++i) {
                int chunk = i * 256 + tid;
                int row = chunk >> 4, c8 = chunk & 15;
                int n = n0 + row;
                float4 v0 = make_float4(0.f, 0.f, 0.f, 0.f), v1 = v0;
                if (n < N_NODES) {
                    const float4* g = (const float4*)(x + (size_t)n * FEAT + c8 * 8);
                    v0 = g[0]; v1 = g[1];
                }
                unsigned short hh[8];
                hh[0] = f2b(v0.x); hh[1] = f2b(v0.y); hh[2] = f2b(v0.z); hh[3] = f2b(v0.w);
                hh[4] = f2b(v1.x); hh[5] = f2b(v1.y); hh[6] = f2b(v1.z); hh[7] = f2b(v1.w);
                int byte = (row * 256 + c8 * 16) ^ ((row & 7) << 4);
                *(bf16x8*)((char*)xs + byte) = *(bf16x8*)hh;
            }
        } else if (pass == 0) {
            // x bf16 row-major
            const unsigned short* xb = (const unsigned short*)xv;
#pragma unroll
            for (int i = 0; i < 4; ++i) {
                int chunk = i * 256 + tid;
                int row = chunk >> 4, c8 = chunk & 15;
                int n = n0 + row;
                float4 v = make_float4(0.f, 0.f, 0.f, 0.f);
                if (n < N_NODES) v = *(const float4*)(xb + (size_t)n * FEAT + c8 * 8);
                int byte = (row * 256 + c8 * 16) ^ ((row & 7) << 4);
                *(float4*)((char*)xs + byte) = v;
            }
        } else {
            // p SLICE-MAJOR [s][n][16]; lane-fastest-over-rows for coalescing
#pragma unroll
            for (int i = 0; i < 4; ++i) {
                int chunk = i * 256 + tid;
                int row = chunk & 63;          // node-in-tile
                int c8 = chunk >> 6;           // 8-feat group 0..15 (slice = c8>>1)
                int n = n0 + row;
                float4 v = make_float4(0.f, 0.f, 0.f, 0.f);
                if (n < N_NODES)
                    v = *(const float4*)(p + ((size_t)(c8 >> 1) * N_NODES + n) * 16 + (c8 & 1) * 8);
                int byte = (row * 256 + c8 * 16) ^ ((row & 7) << 4);
                *(float4*)((char*)xs + byte) = v;
            }
        }
        __syncthreads();

        const unsigned short* Wt = pass ? W2t : W1t;
        bf16x8 xfrag[4];
#pragma unroll
        for (int kk = 0; kk < 4; ++kk) {
            int byte = (nrow * 256 + (kk * 32 + lhi * 8) * 2) ^ ((nrow & 7) << 4);
            xfrag[kk] = *(const bf16x8*)((const char*)xs + byte);
        }
#pragma unroll
        for (int ft = 0; ft < 8; ++ft) {
            const unsigned short* wrow = Wt + (size_t)(ft * 16 + l15) * FEAT;
#pragma unroll
            for (int kk = 0; kk < 4; ++kk) {
                bf16x8 wfrag = *(const bf16x8*)(wrow + kk * 32 + lhi * 8);
                acc[ft] = __builtin_amdgcn_mfma_f32_16x16x32_bf16(wfrag, xfrag[kk], acc[ft], 0, 0, 0);
            }
        }
    }

    // epilogue 1: bias + relu; wide stores (lane owns node nglob, 4 feats per ft)
    if (MODE == 1) __syncthreads();  // all xs reads done before x' overwrite
#pragma unroll
    for (int ft = 0; ft < 8; ++ft) {
        float4 bv = ((const float4*)bias)[ft * 4 + lhi];
        float v0 = fmaxf(acc[ft][0] + bv.x, 0.f);
        float v1 = fmaxf(acc[ft][1] + bv.y, 0.f);
        float v2 = fmaxf(acc[ft][2] + bv.z, 0.f);
        float v3 = fmaxf(acc[ft][3] + bv.w, 0.f);
        uint2 pk = make_uint2((unsigned)f2b(v0) | ((unsigned)f2b(v1) << 16),
                              (unsigned)f2b(v2) | ((unsigned)f2b(v3) << 16));
        if (MODE == 0) {
            if (nglob < N_NODES)
                *(uint2*)(yh + ((size_t)ft * N_NODES + nglob) * 16 + fsub) = pk;
        } else if (MODE == 2) {
            if (nglob < N_NODES)
                *(float4*)(yf + (size_t)nglob * FEAT + ft * 16 + fsub) = make_float4(v0, v1, v2, v3);
        } else {
            if (nglob < N_NODES)
                *(uint2*)(yx + (size_t)nglob * FEAT + ft * 16 + fsub) = pk;
            int byte = (nrow * 256 + (ft * 16 + fsub) * 2) ^ ((nrow & 7) << 4);
            *(uint2*)((char*)xs + byte) = pk;
        }
    }

    // pass 3 (MODE 1): h' = relu(x' @ Wnt + bias_n) -> slice-major
    if (MODE == 1) {
        __syncthreads();
#pragma unroll
        for (int t = 0; t < 8; ++t) acc[t] = (f32x4)(0.f);
        bf16x8 xfrag[4];
#pragma unroll
        for (int kk = 0; kk < 4; ++kk) {
            int byte = (nrow * 256 + (kk * 32 + lhi * 8) * 2) ^ ((nrow & 7) << 4);
            xfrag[kk] = *(const bf16x8*)((const char*)xs + byte);
        }
#pragma unroll
        for (int ft = 0; ft < 8; ++ft) {
            const unsigned short* wrow = Wnt + (size_t)(ft * 16 + l15) * FEAT;
#pragma unroll
            for (int kk = 0; kk < 4; ++kk) {
                bf16x8 wfrag = *(const bf16x8*)(wrow + kk * 32 + lhi * 8);
                acc[ft] = __builtin_amdgcn_mfma_f32_16x16x32_bf16(wfrag, xfrag[kk], acc[ft], 0, 0, 0);
            }
        }
#pragma unroll
        for (int ft = 0; ft < 8; ++ft) {
            float4 bv = ((const float4*)bias_n)[ft * 4 + lhi];
            float v0 = fmaxf(acc[ft][0] + bv.x, 0.f);
            float v1 = fmaxf(acc[ft][1] + bv.y, 0.f);
            float v2 = fmaxf(acc[ft][2] + bv.z, 0.f);
            float v3 = fmaxf(acc[ft][3] + bv.w, 0.f);
            uint2 pk = make_uint2((unsigned)f2b(v0) | ((unsigned)f2b(v1) << 16),
                                  (unsigned)f2b(v2) | ((unsigned)f2b(v3) << 16));
            if (nglob < N_NODES)
                *(uint2*)(yh + ((size_t)ft * N_NODES + nglob) * 16 + fsub) = pk;
        }
    }
}

// ---------------- segment max, XCD-pinned slices, 4-node ILP ----------------
// h slice-major: hs[s][node][16 feats] bf16 (3.2 MB/slice -> one XCD L2).
// pooled output ALSO slice-major (full-line XCD-local writes).
__global__ __launch_bounds__(256) void seg_max_kernel(
    const unsigned short* __restrict__ hs, const int* __restrict__ row_ptr,
    const int* __restrict__ edge_src, unsigned short* __restrict__ pooled) {
    const int s = blockIdx.x & 7;
    const int g = blockIdx.x >> 3;            // node group of 16
    const int wv = threadIdx.x >> 6;
    const int lane = threadIdx.x & 63;
    const int qn = lane >> 4;                 // node-in-wave 0..3
    const int slot = (lane >> 2) & 3;         // edge slot 0..3
    const int f = lane & 3;                   // feat quad 0..3
    int node = g * 16 + wv * 4 + qn;
    const bool valid = node < N_NODES;
    node = valid ? node : N_NODES - 1;
    const unsigned short* hbase = hs + (size_t)s * N_NODES * 16;

    const int start = row_ptr[node];
    const int end = row_ptr[node + 1];
    unsigned int a0 = 0u, a1 = 0u;            // packed 4x bf16 (>=0)
    int i = start + slot;
    for (; i + 4 < end; i += 8) {
        const uint2 v0 = *(const uint2*)(hbase + (size_t)edge_src[i] * 16 + f * 4);
        const uint2 v1 = *(const uint2*)(hbase + (size_t)edge_src[i + 4] * 16 + f * 4);
        a0 = pkmax(a0, v0.x); a1 = pkmax(a1, v0.y);
        a0 = pkmax(a0, v1.x); a1 = pkmax(a1, v1.y);
    }
    if (i < end) {
        const uint2 v0 = *(const uint2*)(hbase + (size_t)edge_src[i] * 16 + f * 4);
        a0 = pkmax(a0, v0.x); a1 = pkmax(a1, v0.y);
    }
    a0 = pkmax(a0, __shfl_xor(a0, 4, 64));
    a1 = pkmax(a1, __shfl_xor(a1, 4, 64));
    a0 = pkmax(a0, __shfl_xor(a0, 8, 64));
    a1 = pkmax(a1, __shfl_xor(a1, 8, 64));
    if (slot == 0 && valid) {
        *(uint2*)(pooled + ((size_t)s * N_NODES + node) * 16 + f * 4) = make_uint2(a0, a1);
    }
}

// ---------------- launch ----------------
// ws (~148 MB < proven 161): edge_src 6.4 | ebuf 12.8 | deg 0.4 | bkt_cnt 1K |
// row_ptr 0.4 | blk_sums 2K | bkt_start 1K | bkt_cursor 1K | wt 0.39 |
// bufH 25.6 (slice-major) | bufP 25.6 (slice-major) | bufX0 25.6 | bufX1 25.6
// x chain: feats(f32) -> X0 -> X1 -> X0 -> d_out(f32)

extern "C" void kernel_launch(void* const* d_in, const int* in_sizes, int n_in,
                              void* d_out, int out_size, void* d_ws, size_t ws_size,
                              hipStream_t stream) {
    const float* feats = (const float*)d_in[0];
    const float* Wp = (const float*)d_in[1];
    const float* bp = (const float*)d_in[2];
    const float* Ws = (const float*)d_in[3];
    const float* Wn = (const float*)d_in[4];
    const float* bb = (const float*)d_in[5];
    const int* src = (const int*)d_in[6];
    const int* dst = (const int*)d_in[7];
    float* out = (float*)d_out;

    const size_t NF = (size_t)N_NODES * FEAT;
    char* ws = (char*)d_ws;
    int* edge_src = (int*)ws;    ws += (size_t)N_EDGES * sizeof(int);
    int2* ebuf = (int2*)ws;      ws += (size_t)N_EDGES * sizeof(int2);
    int* deg = (int*)ws;         ws += (size_t)N_NODES * sizeof(int);
    int* bkt_cnt = (int*)ws;     ws += 256 * sizeof(int);
    int* row_ptr = (int*)ws;     ws += (size_t)(N_NODES + 4) * sizeof(int);
    int* blk_sums = (int*)ws;    ws += 512 * sizeof(int);
    int* bkt_start = (int*)ws;   ws += 256 * sizeof(int);
    int* bkt_cursor = (int*)ws;  ws += 256 * sizeof(int);
    unsigned short* wt = (unsigned short*)ws;    ws += (size_t)12 * 16384 * sizeof(unsigned short);
    unsigned short* bufH = (unsigned short*)ws;  ws += NF * sizeof(unsigned short);
    unsigned short* bufP = (unsigned short*)ws;  ws += NF * sizeof(unsigned short);
    unsigned short* bufX0 = (unsigned short*)ws; ws += NF * sizeof(unsigned short);
    unsigned short* bufX1 = (unsigned short*)ws;

    // CSR build (deg & bkt_cnt adjacent -> single memset)
    hipMemsetAsync(deg, 0, ((size_t)N_NODES + 256) * sizeof(int), stream);
    count_deg_kernel<<<N_P1_BLKS, 256, 0, stream>>>(dst, deg, bkt_cnt);
    blk_sum_kernel<<<N_SCAN_BLKS, SCAN_BLK, 0, stream>>>(deg, blk_sums);
    scan_all_kernel<<<1, 512, 0, stream>>>(blk_sums, bkt_cnt, bkt_start, bkt_cursor);
    write_rowptr_kernel<<<N_SCAN_BLKS, SCAN_BLK, 0, stream>>>(deg, blk_sums, row_ptr);
    bucket_scatter_kernel<<<N_P1_BLKS, 256, 0, stream>>>(src, dst, bkt_cursor, ebuf);
    csr_scatter_kernel<<<NBKT, 256, 0, stream>>>(ebuf, bkt_start, row_ptr, edge_src);
    convert_wt_kernel<<<48, 256, 0, stream>>>(Wp, Ws, Wn, wt);

    const int gemm_grid = (N_NODES + 63) / 64;        // 1563
    const int seg_grid = ((N_NODES + 15) / 16) * 8;   // 6250 groups x 8 slices

    const unsigned short* xb[LAYERS] = {nullptr, bufX0, bufX1, bufX0};
    unsigned short* xo[LAYERS] = {bufX0, bufX1, bufX0, nullptr};

    // layer 0 h_pool
    gemm_kernel<0, true><<<gemm_grid, 256, 0, stream>>>(
        feats, nullptr, wt, nullptr, bp, nullptr, nullptr, nullptr, nullptr, bufH);

    for (int l = 0; l < LAYERS; ++l) {
        const unsigned short* WsT = wt + (size_t)(4 + l) * 16384;
        const unsigned short* WnT = wt + (size_t)(8 + l) * 16384;
        const float* bl = bb + (size_t)l * FEAT;

        seg_max_kernel<<<seg_grid, 256, 0, stream>>>(bufH, row_ptr, edge_src, bufP);

        if (l == 0) {
            gemm_kernel<1, true><<<gemm_grid, 256, 0, stream>>>(
                feats, bufP, WsT, WnT, bl, wt + (size_t)(l + 1) * 16384,
                bp + (size_t)(l + 1) * FEAT, nullptr, xo[l], bufH);
        } else if (l < LAYERS - 1) {
            gemm_kernel<1, false><<<gemm_grid, 256, 0, stream>>>(
                xb[l], bufP, WsT, WnT, bl, wt + (size_t)(l + 1) * 16384,
                bp + (size_t)(l + 1) * FEAT, nullptr, xo[l], bufH);
        } else {
            gemm_kernel<2, false><<<gemm_grid, 256, 0, stream>>>(
                xb[l], bufP, WsT, WnT, bl, nullptr, nullptr, out, nullptr, nullptr);
        }
    }
}